// Round 1
// baseline (3051.633 us; speedup 1.0000x reference)
//
#include <hip/hip_runtime.h>
#include <hip/hip_bf16.h>

// Problem dims (fixed by reference)
#define PD 128   // packets
#define BD 32    // batch
#define SD 64    // bytes per packet (byte-GRU seq len)
#define ED 50    // embedding size
#define EP 52    // padded E (16B-aligned float4 rows)
#define HD 128   // hidden (byte and packet)
#define GD 384   // 3*H gates
#define ND 4096  // P*B byte-level batch

__device__ __forceinline__ float sigm(float x) { return 1.0f / (1.0f + __expf(-x)); }
__device__ __forceinline__ float tanh_f(float x) { return 1.0f - 2.0f / (__expf(2.0f * x) + 1.0f); }

// ---------------------------------------------------------------------------
// Prep: pad Wih rows (2,384,50) -> (2,384,52) with zeros, for aligned float4.
// ---------------------------------------------------------------------------
__global__ void prep_pad_wih(const float* __restrict__ bw, const float* __restrict__ pw,
                             float* __restrict__ bP, float* __restrict__ pP) {
    int idx = blockIdx.x * 256 + threadIdx.x;
    if (idx >= 2 * GD * EP) return;
    int row = idx / EP, e = idx - row * EP;
    float vb = 0.f, vp = 0.f;
    if (e < ED) { vb = bw[row * ED + e]; vp = pw[row * ED + e]; }
    bP[idx] = vb; pP[idx] = vp;
}

// ---------------------------------------------------------------------------
// K1: byte-level bi-GRU. Persistent: block = (dir, 32-sequence chunk).
// h double-buffered in LDS; fused embed-gather + input projection per step.
// Writes y (bf16, [S][N][256]) and hn (f32, [2][N][128]).
// ---------------------------------------------------------------------------
__global__ __launch_bounds__(512, 2) void byte_gru(
    const int* __restrict__ flow, const float* __restrict__ emb,
    const float* __restrict__ WihP, const float* __restrict__ Whh,
    const float* __restrict__ h0b,
    __hip_bfloat16* __restrict__ y, float* __restrict__ hn) {
    const int dir   = blockIdx.x >> 7;
    const int chunk = blockIdx.x & 127;
    const int n0    = chunk * 32;
    const int tid   = threadIdx.x;
    const int i2    = tid & 15;   // sequence pair -> rows 2*i2, 2*i2+1
    const int gg    = tid >> 4;   // 0..31 ; gates g = gg + 32*j, j<12

    __shared__ float hbuf[2][32][132];  // stride 132: 16B aligned, mild conflicts only
    __shared__ float xs[2][32][EP];

    // h0_bytes[p][dir][b][u], p == chunk, b == row
    for (int idx = tid; idx < 32 * HD; idx += 512) {
        int ii = idx >> 7, u = idx & 127;
        hbuf[0][ii][u] = h0b[((chunk * 2 + dir) * 32 + ii) * HD + u];
    }
    // zero xs pads (cols 50,51) in both buffers: never written by staging
    if (tid < 128) {
        int bb = tid >> 6, ii = (tid >> 1) & 31, e = ED + (tid & 1);
        xs[bb][ii][e] = 0.f;
    }

    const float* WhhD = Whh + dir * GD * HD;
    const float* WihD = WihP + dir * GD * EP;
    const int r0 = 2 * i2, r1 = r0 + 1;

    for (int t = 0; t < SD; ++t) {
        const int par = t & 1;
        const int s   = dir ? (SD - 1 - t) : t;

        // stage x_s: gather 32 embedding rows (float2: rows are 8B-aligned)
        for (int idx = tid; idx < 32 * 25; idx += 512) {
            int ii = idx / 25, e2 = idx - ii * 25;
            int row = flow[(n0 + ii) * SD + s];
            *(float2*)&xs[par][ii][2 * e2] = *(const float2*)&emb[row * ED + 2 * e2];
        }
        __syncthreads();  // xs ready; also fences previous step's h writes

        float aH0[12], aH1[12], aX0[12], aX1[12];
        #pragma unroll
        for (int j = 0; j < 12; ++j) { aH0[j] = 0.f; aH1[j] = 0.f; aX0[j] = 0.f; aX1[j] = 0.f; }

        const float* h0p = &hbuf[par][r0][0];
        const float* h1p = &hbuf[par][r1][0];
        #pragma unroll 2
        for (int kc = 0; kc < 32; ++kc) {
            float4 ha = *(const float4*)(h0p + kc * 4);
            float4 hb = *(const float4*)(h1p + kc * 4);
            #pragma unroll
            for (int j = 0; j < 12; ++j) {
                float4 w4 = *(const float4*)(WhhD + (gg + 32 * j) * HD + kc * 4);
                aH0[j] += ha.x * w4.x + ha.y * w4.y + ha.z * w4.z + ha.w * w4.w;
                aH1[j] += hb.x * w4.x + hb.y * w4.y + hb.z * w4.z + hb.w * w4.w;
            }
        }
        const float* x0p = &xs[par][r0][0];
        const float* x1p = &xs[par][r1][0];
        #pragma unroll 2
        for (int ec = 0; ec < 13; ++ec) {
            float4 xa = *(const float4*)(x0p + ec * 4);
            float4 xb = *(const float4*)(x1p + ec * 4);
            #pragma unroll
            for (int j = 0; j < 12; ++j) {
                float4 w4 = *(const float4*)(WihD + (gg + 32 * j) * EP + ec * 4);
                aX0[j] += xa.x * w4.x + xa.y * w4.y + xa.z * w4.z + xa.w * w4.w;
                aX1[j] += xb.x * w4.x + xb.y * w4.y + xb.z * w4.z + xb.w * w4.w;
            }
        }
        // gates: unit u = gg + 32*jj ; r at j=jj, z at j=jj+4, n at j=jj+8
        #pragma unroll
        for (int jj = 0; jj < 4; ++jj) {
            const int u = gg + 32 * jj;
            {
                float r = sigm(aX0[jj] + aH0[jj]);
                float z = sigm(aX0[jj + 4] + aH0[jj + 4]);
                float nn = tanh_f(aX0[jj + 8] + r * aH0[jj + 8]);
                float hnew = (1.f - z) * nn + z * hbuf[par][r0][u];
                hbuf[1 - par][r0][u] = hnew;
                y[((s * ND) + n0 + r0) * 256 + dir * HD + u] = __float2bfloat16(hnew);
            }
            {
                float r = sigm(aX1[jj] + aH1[jj]);
                float z = sigm(aX1[jj + 4] + aH1[jj + 4]);
                float nn = tanh_f(aX1[jj + 8] + r * aH1[jj + 8]);
                float hnew = (1.f - z) * nn + z * hbuf[par][r1][u];
                hbuf[1 - par][r1][u] = hnew;
                y[((s * ND) + n0 + r1) * 256 + dir * HD + u] = __float2bfloat16(hnew);
            }
        }
        // no trailing barrier: next iteration's barrier fences h[1-par] writes
    }
    __syncthreads();
    // after t=63 the final h sits in hbuf[0]
    for (int idx = tid; idx < 32 * HD; idx += 512) {
        int ii = idx >> 7, u = idx & 127;
        hn[(dir * ND + n0 + ii) * HD + u] = hbuf[0][ii][u];
    }
}

// ---------------------------------------------------------------------------
// K2: byte attention + enc projection. Block = one (p,b) sequence.
// hn_p reshape quirk handled via raw C-order flat-index decode.
// ---------------------------------------------------------------------------
__global__ __launch_bounds__(256) void byte_attn(
    const __hip_bfloat16* __restrict__ y, const float* __restrict__ hn,
    const float* __restrict__ aW, const float* __restrict__ ab,
    float* __restrict__ enc) {
    const int n = blockIdx.x;
    const int p = n >> 5, irow = n & 31;
    const int tid = threadIdx.x;
    __shared__ __hip_bfloat16 yl[SD][256];
    __shared__ float hnl[256];
    __shared__ float red[256];
    __shared__ float awl[SD];
    __shared__ float ctxl[256];

    // stage y[:, n, :] (32KB) via 16B chunks
    for (int idx = tid; idx < SD * 32; idx += 256) {
        int s = idx >> 5, cc = (idx & 31) * 8;
        *(uint4*)&yl[s][cc] = *(const uint4*)&y[((s * ND) + n) * 256 + cc];
    }
    {   // hn_p[p][irow][c] = hn[d][p*32+bb][u], flat idx = irow*256+c over (2,32,128)
        int c = tid;
        int idx = irow * 256 + c;
        int d = idx >> 12, bb = (idx >> 7) & 31, u = idx & 127;
        hnl[c] = hn[(d * ND + p * 32 + bb) * HD + u];
    }
    __syncthreads();
    {   // scores: lane s, skewed c order to break the 512B-stride bank conflict
        int s = tid & 63, grp = tid >> 6;
        float acc = 0.f;
        for (int k = 0; k < 64; ++k) {
            int c = grp * 64 + ((s + k) & 63);
            acc += __bfloat162float(yl[s][c]) * hnl[c];
        }
        red[grp * 64 + s] = acc;
    }
    __syncthreads();
    if (tid < 64) {
        float sc = red[tid] + red[64 + tid] + red[128 + tid] + red[192 + tid];
        float m = sc;
        #pragma unroll
        for (int o = 32; o; o >>= 1) m = fmaxf(m, __shfl_xor(m, o));
        float e = __expf(sc - m);
        float ssum = e;
        #pragma unroll
        for (int o = 32; o; o >>= 1) ssum += __shfl_xor(ssum, o);
        awl[tid] = e / ssum;
    }
    __syncthreads();
    {   // ctx[c]
        int c = tid;
        float acc = 0.f;
        for (int s = 0; s < SD; ++s) acc += awl[s] * __bfloat162float(yl[s][c]);
        ctxl[c] = acc;
    }
    __syncthreads();
    {   // enc[e] = ctx . attn_W[e,:] + b[e]  (50x256), 4 partials per e
        int e = tid & 63, q = tid >> 6;
        float acc = 0.f;
        if (e < ED) {
            for (int c = q * 64; c < q * 64 + 64; ++c) acc += ctxl[c] * aW[e * 256 + c];
        }
        red[q * 64 + e] = acc;
    }
    __syncthreads();
    if (tid < EP) {
        float v = 0.f;
        if (tid < ED) v = red[tid] + red[64 + tid] + red[128 + tid] + red[192 + tid] + ab[tid];
        enc[n * EP + tid] = v;   // pads written as 0
    }
}

// ---------------------------------------------------------------------------
// K2.5: packet-GRU input projection  pxw[d][p][b][g] = enc[p,b,:] . Wih[d][g,:]
// ---------------------------------------------------------------------------
__global__ __launch_bounds__(256, 1) void pkt_xw(
    const float* __restrict__ enc, const float* __restrict__ WihPp,
    float* __restrict__ pxw) {
    const int d = blockIdx.x >> 7, p = blockIdx.x & 127;
    const int tid = threadIdx.x;
    __shared__ float el[32][EP];
    for (int idx = tid; idx < 32 * EP; idx += 256) {
        int ii = idx / EP, e = idx - ii * EP;
        el[ii][e] = enc[(p * 32 + ii) * EP + e];
    }
    __syncthreads();
    const int irow = tid & 31, gg = tid >> 5;  // gates g = gg + 8*j, j<48
    const float* W = WihPp + d * GD * EP;
    float acc[48];
    #pragma unroll
    for (int j = 0; j < 48; ++j) acc[j] = 0.f;
    for (int ec = 0; ec < 13; ++ec) {
        float4 x4 = *(const float4*)&el[irow][ec * 4];
        #pragma unroll
        for (int j = 0; j < 48; ++j) {
            float4 w4 = *(const float4*)(W + (gg + 8 * j) * EP + ec * 4);
            acc[j] += x4.x * w4.x + x4.y * w4.y + x4.z * w4.z + x4.w * w4.w;
        }
    }
    float* dst = pxw + (size_t)((d * PD + p) * 32 + irow) * GD;
    #pragma unroll
    for (int j = 0; j < 48; ++j) dst[gg + 8 * j] = acc[j];
}

// ---------------------------------------------------------------------------
// K3: packet-level bi-GRU. Block = (dir, batch-seq): 64 blocks, 384 threads.
// Whh row (128 f32) held in registers per thread (g = tid) across all steps.
// ---------------------------------------------------------------------------
__global__ __launch_bounds__(384, 1) void pkt_gru(
    const float* __restrict__ pxw, const float* __restrict__ Whh,
    const float* __restrict__ h0p,
    float* __restrict__ y2, float* __restrict__ hn2) {
    const int d = blockIdx.x >> 5, sq = blockIdx.x & 31;
    const int tid = threadIdx.x;  // 384 = one gate each
    __shared__ float hcur[HD];
    __shared__ float hw[GD];
    float w[HD];
    const float* wrow = Whh + (d * GD + tid) * HD;
    #pragma unroll
    for (int k = 0; k < HD; ++k) w[k] = wrow[k];
    if (tid < HD) hcur[tid] = h0p[(d * 32 + sq) * HD + tid];
    __syncthreads();
    for (int t = 0; t < PD; ++t) {
        const int pp = d ? (PD - 1 - t) : t;
        float a0 = 0.f, a1 = 0.f, a2 = 0.f, a3 = 0.f;
        #pragma unroll
        for (int kc = 0; kc < 32; ++kc) {
            float4 h4 = *(const float4*)&hcur[kc * 4];   // uniform addr -> broadcast
            a0 += w[4 * kc + 0] * h4.x; a1 += w[4 * kc + 1] * h4.y;
            a2 += w[4 * kc + 2] * h4.z; a3 += w[4 * kc + 3] * h4.w;
        }
        hw[tid] = (a0 + a1) + (a2 + a3);
        __syncthreads();           // hw ready; all matvec reads of hcur done
        if (tid < HD) {
            const float* xw = pxw + (size_t)((d * PD + pp) * 32 + sq) * GD;
            int u = tid;
            float r = sigm(xw[u] + hw[u]);
            float z = sigm(xw[HD + u] + hw[HD + u]);
            float nn = tanh_f(xw[2 * HD + u] + r * hw[2 * HD + u]);
            float hnew = (1.f - z) * nn + z * hcur[u];
            hcur[u] = hnew;
            y2[(pp * 32 + sq) * 256 + d * HD + u] = hnew;
        }
        __syncthreads();           // hcur updated before next matvec
    }
    if (tid < HD) hn2[(d * 32 + sq) * HD + tid] = hcur[tid];
}

// ---------------------------------------------------------------------------
// K4: packet attention + output head. Block = one batch element.
// hn2v reshape quirk: hn2v[b][c] = hn2[b>>4][2*(b&15)+(c>>7)][c&127]
// ---------------------------------------------------------------------------
__global__ __launch_bounds__(256) void pkt_attn_cls(
    const float* __restrict__ y2, const float* __restrict__ hn2,
    const float* __restrict__ aW, const float* __restrict__ ab,
    const float* __restrict__ cW, const float* __restrict__ cb,
    float* __restrict__ out) {
    const int b = blockIdx.x;
    const int tid = threadIdx.x;
    __shared__ float hnl[256];
    __shared__ float red[256];
    __shared__ float scl[PD];
    __shared__ float awl[PD];
    __shared__ float ctxl[256];
    __shared__ float ol[HD];
    {
        int c = tid;
        hnl[c] = hn2[(((b >> 4) * 32) + 2 * (b & 15) + (c >> 7)) * HD + (c & 127)];
    }
    __syncthreads();
    {   // scores over p: thread (p2, half)
        int p2 = tid >> 1, hf = tid & 1;
        const float* yr = y2 + (p2 * 32 + b) * 256 + hf * 128;
        const float* hr = hnl + hf * 128;
        float acc = 0.f;
        for (int c = 0; c < 128; ++c) acc += yr[c] * hr[c];
        red[hf * 128 + p2] = acc;
    }
    __syncthreads();
    if (tid < PD) scl[tid] = red[tid] + red[128 + tid];
    __syncthreads();
    if (tid < 64) {  // softmax over 128 with one wave, 2 per lane
        float s0 = scl[tid], s1 = scl[64 + tid];
        float m = fmaxf(s0, s1);
        #pragma unroll
        for (int o = 32; o; o >>= 1) m = fmaxf(m, __shfl_xor(m, o));
        float e0 = __expf(s0 - m), e1 = __expf(s1 - m);
        float ss = e0 + e1;
        #pragma unroll
        for (int o = 32; o; o >>= 1) ss += __shfl_xor(ss, o);
        awl[tid] = e0 / ss; awl[64 + tid] = e1 / ss;
    }
    __syncthreads();
    {   // ctx2[c]
        int c = tid;
        float acc = 0.f;
        for (int p2 = 0; p2 < PD; ++p2) acc += awl[p2] * y2[(p2 * 32 + b) * 256 + c];
        ctxl[c] = acc;
    }
    __syncthreads();
    {   // o[h] = ctx2 . pkt_attn_W[h,:] + b[h]
        int h = tid >> 1, hf = tid & 1;
        const float* wr = aW + h * 256 + hf * 128;
        const float* cr = ctxl + hf * 128;
        float acc = 0.f;
        for (int c = 0; c < 128; ++c) acc += cr[c] * wr[c];
        red[hf * 128 + h] = acc;
    }
    __syncthreads();
    if (tid < HD) ol[tid] = red[tid] + red[128 + tid] + ab[tid];
    __syncthreads();
    if (tid < 11) {
        float acc = cb[tid];
        for (int h = 0; h < HD; ++h) acc += ol[h] * cW[tid * HD + h];
        out[b * 11 + tid] = acc;
    }
}

// ---------------------------------------------------------------------------
extern "C" void kernel_launch(void* const* d_in, const int* in_sizes, int n_in,
                              void* d_out, int out_size, void* d_ws, size_t ws_size,
                              hipStream_t stream) {
    const int*   flow = (const int*)d_in[0];
    const float* emb  = (const float*)d_in[1];
    const float* bWih = (const float*)d_in[2];
    const float* bWhh = (const float*)d_in[3];
    const float* baW  = (const float*)d_in[4];
    const float* bab  = (const float*)d_in[5];
    const float* pWih = (const float*)d_in[6];
    const float* pWhh = (const float*)d_in[7];
    const float* paW  = (const float*)d_in[8];
    const float* pab  = (const float*)d_in[9];
    const float* cW   = (const float*)d_in[10];
    const float* cb   = (const float*)d_in[11];
    const float* h0b  = (const float*)d_in[12];
    const float* h0p  = (const float*)d_in[13];
    float* out = (float*)d_out;

    char* ws = (char*)d_ws;
    size_t off = 0;
    __hip_bfloat16* y = (__hip_bfloat16*)(ws + off); off += (size_t)SD * ND * 256 * 2; // 128 MiB
    float* hn    = (float*)(ws + off); off += (size_t)2 * ND * HD * 4;
    float* enc   = (float*)(ws + off); off += (size_t)ND * EP * 4;
    float* pxw   = (float*)(ws + off); off += (size_t)2 * PD * 32 * GD * 4;
    float* y2    = (float*)(ws + off); off += (size_t)PD * 32 * 256 * 4;
    float* hn2   = (float*)(ws + off); off += (size_t)2 * 32 * HD * 4;
    float* WihPb = (float*)(ws + off); off += (size_t)2 * GD * EP * 4;
    float* WihPp = (float*)(ws + off); off += (size_t)2 * GD * EP * 4;
    if (ws_size < off) return;  // signature: output stays 0 => ws too small

    prep_pad_wih<<<(2 * GD * EP + 255) / 256, 256, 0, stream>>>(bWih, pWih, WihPb, WihPp);
    byte_gru<<<256, 512, 0, stream>>>(flow, emb, WihPb, bWhh, h0b, y, hn);
    byte_attn<<<ND, 256, 0, stream>>>(y, hn, baW, bab, enc);
    pkt_xw<<<256, 256, 0, stream>>>(enc, WihPp, pxw);
    pkt_gru<<<64, 384, 0, stream>>>(pxw, pWhh, h0p, y2, hn2);
    pkt_attn_cls<<<32, 256, 0, stream>>>(y2, hn2, paW, pab, cW, cb, out);
}

// Round 2
// 611.261 us; speedup vs baseline: 4.9924x; 4.9924x over previous
//
#include <hip/hip_runtime.h>
#include <hip/hip_bf16.h>

// Problem dims (fixed by reference)
#define PD 128   // packets
#define BD 32    // batch
#define SD 64    // bytes per packet (byte-GRU seq len)
#define ED 50    // embedding size
#define EP 52    // padded E (16B-aligned float4 rows)
#define HD 128   // hidden (byte and packet)
#define GD 384   // 3*H gates
#define ND 4096  // P*B byte-level batch
#define VD 65536 // vocab

typedef __attribute__((ext_vector_type(8))) short bf16x8;
typedef __attribute__((ext_vector_type(4))) float f32x4;

__device__ __forceinline__ float sigm(float x) { return 1.0f / (1.0f + __expf(-x)); }
__device__ __forceinline__ float tanh_f(float x) { return 1.0f - 2.0f / (__expf(2.0f * x) + 1.0f); }

__device__ __forceinline__ unsigned short f2b(float f) {  // f32 -> bf16 raw, RNE
    union { float f; unsigned u; } a; a.f = f;
    unsigned r = a.u + 0x7FFFu + ((a.u >> 16) & 1u);
    return (unsigned short)(r >> 16);
}
__device__ __forceinline__ float b2f(unsigned short h) {
    union { unsigned u; float f; } a; a.u = ((unsigned)h) << 16; return a.f;
}

union frag_u { bf16x8 v; unsigned short s[8]; };

#define MFMA(acc, a, b) acc = __builtin_amdgcn_mfma_f32_16x16x32_bf16(a, b, acc, 0, 0, 0)

// ---------------------------------------------------------------------------
// Prep A: pad+convert embedding (V,50) f32 -> (V,64) bf16 plane (zero pad).
// ---------------------------------------------------------------------------
__global__ void prep_emb(const float* __restrict__ emb, unsigned short* __restrict__ embHi) {
    int idx = blockIdx.x * 256 + threadIdx.x;
    if (idx >= VD * 64) return;
    int row = idx >> 6, e = idx & 63;
    float v = (e < ED) ? emb[row * ED + e] : 0.f;
    embHi[idx] = f2b(v);
}

// ---------------------------------------------------------------------------
// Prep B: pad packet Wih rows (2,384,50) -> (2,384,52) for pkt_xw float4 path.
// ---------------------------------------------------------------------------
__global__ void prep_pad_pkt(const float* __restrict__ pw, float* __restrict__ pP) {
    int idx = blockIdx.x * 256 + threadIdx.x;
    if (idx >= 2 * GD * EP) return;
    int row = idx / EP, e = idx - row * EP;
    pP[idx] = (e < ED) ? pw[row * ED + e] : 0.f;
}

// ---------------------------------------------------------------------------
// K1: byte-level bi-GRU via MFMA with split-bf16 precision compensation.
// Block = (dir, 32-seq chunk), 512 threads = 8 waves; wave w owns units
// [16w,16w+16). Weights live in registers as pre-split B-fragments; h lives
// in LDS as bf16 hi/lo planes (XOR-swizzled); h_old stays in registers.
// 3-product split for h-matvec (ah*bh + al*bh + ah*bl ~ 2^-16 error);
// 2-product for x (x_hi*(W_hi+W_lo)).
// ---------------------------------------------------------------------------
__global__ __launch_bounds__(512, 2) void byte_gru_mfma(
    const int* __restrict__ flow, const unsigned short* __restrict__ embHi,
    const float* __restrict__ Wih, const float* __restrict__ Whh,
    const float* __restrict__ h0b,
    unsigned short* __restrict__ y, float* __restrict__ hn) {
    const int dir   = blockIdx.x >> 7;
    const int chunk = blockIdx.x & 127;
    const int n0    = chunk * 32;
    const int tid   = threadIdx.x;
    const int w     = tid >> 6;       // wave 0..7
    const int lane  = tid & 63;
    const int col   = lane & 15;      // C col / A row / B col
    const int kq    = lane >> 4;      // k quarter
    const int u     = w * 16 + col;   // owned unit

    __shared__ unsigned short HHI[32 * 128];
    __shared__ unsigned short HLO[32 * 128];
    __shared__ int FLOWT[SD * 32];

    // ---- weights -> register B-fragments (loaded once) ----
    bf16x8 WHh[3][4], WHl[3][4], WXh[3][2], WXl[3][2];
    {
        const float* WhhD = Whh + dir * GD * HD;
        #pragma unroll
        for (int g3 = 0; g3 < 3; ++g3) {
            const float* row = WhhD + (g3 * HD + u) * HD;
            #pragma unroll
            for (int kt = 0; kt < 4; ++kt) {
                const int k0 = kt * 32 + kq * 8;
                frag_u h_, l_;
                #pragma unroll
                for (int b = 0; b < 8; ++b) {
                    float v = row[k0 + b];
                    unsigned short hi = f2b(v);
                    h_.s[b] = hi; l_.s[b] = f2b(v - b2f(hi));
                }
                WHh[g3][kt] = h_.v; WHl[g3][kt] = l_.v;
            }
        }
        const float* WihD = Wih + dir * GD * ED;
        #pragma unroll
        for (int g3 = 0; g3 < 3; ++g3) {
            const float* row = WihD + (g3 * HD + u) * ED;
            #pragma unroll
            for (int kx = 0; kx < 2; ++kx) {
                const int k0 = kx * 32 + kq * 8;
                frag_u h_, l_;
                #pragma unroll
                for (int b = 0; b < 8; ++b) {
                    const int e = k0 + b;
                    float v = (e < ED) ? row[e] : 0.f;
                    unsigned short hi = f2b(v);
                    h_.s[b] = hi; l_.s[b] = f2b(v - b2f(hi));
                }
                WXh[g3][kx] = h_.v; WXl[g3][kx] = l_.v;
            }
        }
    }

    // ---- h0: registers (exact f32 for the z-blend) + LDS hi/lo planes ----
    float hreg[2][4];
    {
        const float* h0row = h0b + (size_t)((chunk * 2 + dir) * 32) * HD;
        #pragma unroll
        for (int m = 0; m < 2; ++m)
            #pragma unroll
            for (int j = 0; j < 4; ++j)
                hreg[m][j] = h0row[(m * 16 + kq * 4 + j) * HD + u];
        for (int idx = tid; idx < 32 * HD; idx += 512) {
            int seq = idx >> 7, uu = idx & 127;
            float v = h0row[idx];
            unsigned short hi = f2b(v);
            int sw = seq * 128 + (uu ^ ((seq & 7) << 3));
            HHI[sw] = hi; HLO[sw] = f2b(v - b2f(hi));
        }
        for (int j = tid; j < SD * 32; j += 512) {  // transposed flow cache
            int s = j >> 5, seq = j & 31;
            FLOWT[j] = flow[(n0 + seq) * SD + s];
        }
    }
    __syncthreads();

    for (int t = 0; t < SD; ++t) {
        const int s = dir ? (SD - 1 - t) : t;

        // x A-fragments: direct global bf16x8 loads (issued early)
        bf16x8 xa00, xa01, xa10, xa11;
        {
            int i0 = FLOWT[s * 32 + col];
            int i1 = FLOWT[s * 32 + 16 + col];
            const bf16x8* r0 = (const bf16x8*)(embHi + (size_t)i0 * 64);
            const bf16x8* r1 = (const bf16x8*)(embHi + (size_t)i1 * 64);
            xa00 = r0[kq]; xa01 = r0[4 + kq];
            xa10 = r1[kq]; xa11 = r1[4 + kq];
        }

        f32x4 aR[2], aZ[2], aHN[2], aXN[2];
        const f32x4 zero = {0.f, 0.f, 0.f, 0.f};
        #pragma unroll
        for (int m = 0; m < 2; ++m) { aR[m] = zero; aZ[m] = zero; aHN[m] = zero; aXN[m] = zero; }

        // h-matvec: 4 k-tiles x 3 gates x 3 split-products x 2 m-tiles
        #pragma unroll
        for (int kt = 0; kt < 4; ++kt) {
            const int off = kt * 32 + kq * 8;
            const int sw0 = col * 128 + (off ^ ((col & 7) << 3));
            const int sw1 = sw0 + 16 * 128;   // seq+16 keeps (seq&7)
            bf16x8 ah0 = *(const bf16x8*)&HHI[sw0];
            bf16x8 al0 = *(const bf16x8*)&HLO[sw0];
            bf16x8 ah1 = *(const bf16x8*)&HHI[sw1];
            bf16x8 al1 = *(const bf16x8*)&HLO[sw1];
            MFMA(aR[0], ah0, WHh[0][kt]); MFMA(aR[0], al0, WHh[0][kt]); MFMA(aR[0], ah0, WHl[0][kt]);
            MFMA(aZ[0], ah0, WHh[1][kt]); MFMA(aZ[0], al0, WHh[1][kt]); MFMA(aZ[0], ah0, WHl[1][kt]);
            MFMA(aHN[0], ah0, WHh[2][kt]); MFMA(aHN[0], al0, WHh[2][kt]); MFMA(aHN[0], ah0, WHl[2][kt]);
            MFMA(aR[1], ah1, WHh[0][kt]); MFMA(aR[1], al1, WHh[0][kt]); MFMA(aR[1], ah1, WHl[0][kt]);
            MFMA(aZ[1], ah1, WHh[1][kt]); MFMA(aZ[1], al1, WHh[1][kt]); MFMA(aZ[1], ah1, WHl[1][kt]);
            MFMA(aHN[1], ah1, WHh[2][kt]); MFMA(aHN[1], al1, WHh[2][kt]); MFMA(aHN[1], ah1, WHl[2][kt]);
        }
        // x-projection: 2 k-tiles x 3 gates x 2 products x 2 m-tiles
        #pragma unroll
        for (int kx = 0; kx < 2; ++kx) {
            bf16x8 x0 = kx ? xa01 : xa00;
            bf16x8 x1 = kx ? xa11 : xa10;
            MFMA(aR[0], x0, WXh[0][kx]); MFMA(aR[0], x0, WXl[0][kx]);
            MFMA(aZ[0], x0, WXh[1][kx]); MFMA(aZ[0], x0, WXl[1][kx]);
            MFMA(aXN[0], x0, WXh[2][kx]); MFMA(aXN[0], x0, WXl[2][kx]);
            MFMA(aR[1], x1, WXh[0][kx]); MFMA(aR[1], x1, WXl[0][kx]);
            MFMA(aZ[1], x1, WXh[1][kx]); MFMA(aZ[1], x1, WXl[1][kx]);
            MFMA(aXN[1], x1, WXh[2][kx]); MFMA(aXN[1], x1, WXl[2][kx]);
        }

        // epilogue: gate math in C layout (col=u, row=(lane>>4)*4+j)
        unsigned short yhi[2][4];
        #pragma unroll
        for (int m = 0; m < 2; ++m)
            #pragma unroll
            for (int j = 0; j < 4; ++j) {
                float r = sigm(aR[m][j]);
                float z = sigm(aZ[m][j]);
                float nn = tanh_f(aXN[m][j] + r * aHN[m][j]);
                float hnew = (1.f - z) * nn + z * hreg[m][j];
                hreg[m][j] = hnew;
                yhi[m][j] = f2b(hnew);
            }
        // y stores (global; 16-lane groups write contiguous 32B)
        #pragma unroll
        for (int m = 0; m < 2; ++m)
            #pragma unroll
            for (int j = 0; j < 4; ++j) {
                int seq = m * 16 + kq * 4 + j;
                y[((size_t)(s * ND) + n0 + seq) * 256 + dir * HD + u] = yhi[m][j];
            }
        __syncthreads();   // all A-frag reads of h_t done
        #pragma unroll
        for (int m = 0; m < 2; ++m)
            #pragma unroll
            for (int j = 0; j < 4; ++j) {
                int seq = m * 16 + kq * 4 + j;
                int sw = seq * 128 + (u ^ ((seq & 7) << 3));
                HHI[sw] = yhi[m][j];
                HLO[sw] = f2b(hreg[m][j] - b2f(yhi[m][j]));
            }
        __syncthreads();   // h_{t+1} visible
    }
    // final hidden (exact f32 path)
    #pragma unroll
    for (int m = 0; m < 2; ++m)
        #pragma unroll
        for (int j = 0; j < 4; ++j) {
            int seq = m * 16 + kq * 4 + j;
            hn[((size_t)dir * ND + n0 + seq) * HD + u] = hreg[m][j];
        }
}

// ---------------------------------------------------------------------------
// K2: byte attention + enc projection. Block = one (p,b) sequence.
// ---------------------------------------------------------------------------
__global__ __launch_bounds__(256) void byte_attn(
    const __hip_bfloat16* __restrict__ y, const float* __restrict__ hn,
    const float* __restrict__ aW, const float* __restrict__ ab,
    float* __restrict__ enc) {
    const int n = blockIdx.x;
    const int p = n >> 5, irow = n & 31;
    const int tid = threadIdx.x;
    __shared__ __hip_bfloat16 yl[SD][256];
    __shared__ float hnl[256];
    __shared__ float red[256];
    __shared__ float awl[SD];
    __shared__ float ctxl[256];

    for (int idx = tid; idx < SD * 32; idx += 256) {
        int s = idx >> 5, cc = (idx & 31) * 8;
        *(uint4*)&yl[s][cc] = *(const uint4*)&y[((s * ND) + n) * 256 + cc];
    }
    {   // hn_p reshape quirk: flat idx = irow*256+c over (2,32,128)
        int c = tid;
        int idx = irow * 256 + c;
        int d = idx >> 12, bb = (idx >> 7) & 31, uu = idx & 127;
        hnl[c] = hn[(d * ND + p * 32 + bb) * HD + uu];
    }
    __syncthreads();
    {   // scores, skewed column order to break 512B-stride conflicts
        int s = tid & 63, grp = tid >> 6;
        float acc = 0.f;
        for (int k = 0; k < 64; ++k) {
            int c = grp * 64 + ((s + k) & 63);
            acc += __bfloat162float(yl[s][c]) * hnl[c];
        }
        red[grp * 64 + s] = acc;
    }
    __syncthreads();
    if (tid < 64) {
        float sc = red[tid] + red[64 + tid] + red[128 + tid] + red[192 + tid];
        float m = sc;
        #pragma unroll
        for (int o = 32; o; o >>= 1) m = fmaxf(m, __shfl_xor(m, o));
        float e = __expf(sc - m);
        float ssum = e;
        #pragma unroll
        for (int o = 32; o; o >>= 1) ssum += __shfl_xor(ssum, o);
        awl[tid] = e / ssum;
    }
    __syncthreads();
    {
        int c = tid;
        float acc = 0.f;
        for (int s = 0; s < SD; ++s) acc += awl[s] * __bfloat162float(yl[s][c]);
        ctxl[c] = acc;
    }
    __syncthreads();
    {
        int e = tid & 63, q = tid >> 6;
        float acc = 0.f;
        if (e < ED) {
            for (int c = q * 64; c < q * 64 + 64; ++c) acc += ctxl[c] * aW[e * 256 + c];
        }
        red[q * 64 + e] = acc;
    }
    __syncthreads();
    if (tid < EP) {
        float v = 0.f;
        if (tid < ED) v = red[tid] + red[64 + tid] + red[128 + tid] + red[192 + tid] + ab[tid];
        enc[n * EP + tid] = v;
    }
}

// ---------------------------------------------------------------------------
// K2.5: packet-GRU input projection
// ---------------------------------------------------------------------------
__global__ __launch_bounds__(256, 1) void pkt_xw(
    const float* __restrict__ enc, const float* __restrict__ WihPp,
    float* __restrict__ pxw) {
    const int d = blockIdx.x >> 7, p = blockIdx.x & 127;
    const int tid = threadIdx.x;
    __shared__ float el[32][EP];
    for (int idx = tid; idx < 32 * EP; idx += 256) {
        int ii = idx / EP, e = idx - ii * EP;
        el[ii][e] = enc[(p * 32 + ii) * EP + e];
    }
    __syncthreads();
    const int irow = tid & 31, gg = tid >> 5;
    const float* W = WihPp + d * GD * EP;
    float acc[48];
    #pragma unroll
    for (int j = 0; j < 48; ++j) acc[j] = 0.f;
    for (int ec = 0; ec < 13; ++ec) {
        float4 x4 = *(const float4*)&el[irow][ec * 4];
        #pragma unroll
        for (int j = 0; j < 48; ++j) {
            float4 w4 = *(const float4*)(W + (gg + 8 * j) * EP + ec * 4);
            acc[j] += x4.x * w4.x + x4.y * w4.y + x4.z * w4.z + x4.w * w4.w;
        }
    }
    float* dst = pxw + (size_t)((d * PD + p) * 32 + irow) * GD;
    #pragma unroll
    for (int j = 0; j < 48; ++j) dst[gg + 8 * j] = acc[j];
}

// ---------------------------------------------------------------------------
// K3: packet-level bi-GRU (64 blocks, Whh rows register-resident)
// ---------------------------------------------------------------------------
__global__ __launch_bounds__(384, 1) void pkt_gru(
    const float* __restrict__ pxw, const float* __restrict__ Whh,
    const float* __restrict__ h0p,
    float* __restrict__ y2, float* __restrict__ hn2) {
    const int d = blockIdx.x >> 5, sq = blockIdx.x & 31;
    const int tid = threadIdx.x;
    __shared__ float hcur[HD];
    __shared__ float hw[GD];
    float w[HD];
    const float* wrow = Whh + (d * GD + tid) * HD;
    #pragma unroll
    for (int k = 0; k < HD; ++k) w[k] = wrow[k];
    if (tid < HD) hcur[tid] = h0p[(d * 32 + sq) * HD + tid];
    __syncthreads();
    for (int t = 0; t < PD; ++t) {
        const int pp = d ? (PD - 1 - t) : t;
        float a0 = 0.f, a1 = 0.f, a2 = 0.f, a3 = 0.f;
        #pragma unroll
        for (int kc = 0; kc < 32; ++kc) {
            float4 h4 = *(const float4*)&hcur[kc * 4];
            a0 += w[4 * kc + 0] * h4.x; a1 += w[4 * kc + 1] * h4.y;
            a2 += w[4 * kc + 2] * h4.z; a3 += w[4 * kc + 3] * h4.w;
        }
        hw[tid] = (a0 + a1) + (a2 + a3);
        __syncthreads();
        if (tid < HD) {
            const float* xw = pxw + (size_t)((d * PD + pp) * 32 + sq) * GD;
            int uu = tid;
            float r = sigm(xw[uu] + hw[uu]);
            float z = sigm(xw[HD + uu] + hw[HD + uu]);
            float nn = tanh_f(xw[2 * HD + uu] + r * hw[2 * HD + uu]);
            float hnew = (1.f - z) * nn + z * hcur[uu];
            hcur[uu] = hnew;
            y2[(pp * 32 + sq) * 256 + d * HD + uu] = hnew;
        }
        __syncthreads();
    }
    if (tid < HD) hn2[(d * 32 + sq) * HD + tid] = hcur[tid];
}

// ---------------------------------------------------------------------------
// K4: packet attention + output head
// ---------------------------------------------------------------------------
__global__ __launch_bounds__(256) void pkt_attn_cls(
    const float* __restrict__ y2, const float* __restrict__ hn2,
    const float* __restrict__ aW, const float* __restrict__ ab,
    const float* __restrict__ cW, const float* __restrict__ cb,
    float* __restrict__ out) {
    const int b = blockIdx.x;
    const int tid = threadIdx.x;
    __shared__ float hnl[256];
    __shared__ float red[256];
    __shared__ float scl[PD];
    __shared__ float awl[PD];
    __shared__ float ctxl[256];
    __shared__ float ol[HD];
    {
        int c = tid;
        hnl[c] = hn2[(((b >> 4) * 32) + 2 * (b & 15) + (c >> 7)) * HD + (c & 127)];
    }
    __syncthreads();
    {
        int p2 = tid >> 1, hf = tid & 1;
        const float* yr = y2 + (p2 * 32 + b) * 256 + hf * 128;
        const float* hr = hnl + hf * 128;
        float acc = 0.f;
        for (int c = 0; c < 128; ++c) acc += yr[c] * hr[c];
        red[hf * 128 + p2] = acc;
    }
    __syncthreads();
    if (tid < PD) scl[tid] = red[tid] + red[128 + tid];
    __syncthreads();
    if (tid < 64) {
        float s0 = scl[tid], s1 = scl[64 + tid];
        float m = fmaxf(s0, s1);
        #pragma unroll
        for (int o = 32; o; o >>= 1) m = fmaxf(m, __shfl_xor(m, o));
        float e0 = __expf(s0 - m), e1 = __expf(s1 - m);
        float ss = e0 + e1;
        #pragma unroll
        for (int o = 32; o; o >>= 1) ss += __shfl_xor(ss, o);
        awl[tid] = e0 / ss; awl[64 + tid] = e1 / ss;
    }
    __syncthreads();
    {
        int c = tid;
        float acc = 0.f;
        for (int p2 = 0; p2 < PD; ++p2) acc += awl[p2] * y2[(p2 * 32 + b) * 256 + c];
        ctxl[c] = acc;
    }
    __syncthreads();
    {
        int h = tid >> 1, hf = tid & 1;
        const float* wr = aW + h * 256 + hf * 128;
        const float* cr = ctxl + hf * 128;
        float acc = 0.f;
        for (int c = 0; c < 128; ++c) acc += cr[c] * wr[c];
        red[hf * 128 + h] = acc;
    }
    __syncthreads();
    if (tid < HD) ol[tid] = red[tid] + red[128 + tid] + ab[tid];
    __syncthreads();
    if (tid < 11) {
        float acc = cb[tid];
        for (int h = 0; h < HD; ++h) acc += ol[h] * cW[tid * HD + h];
        out[b * 11 + tid] = acc;
    }
}

// ---------------------------------------------------------------------------
extern "C" void kernel_launch(void* const* d_in, const int* in_sizes, int n_in,
                              void* d_out, int out_size, void* d_ws, size_t ws_size,
                              hipStream_t stream) {
    const int*   flow = (const int*)d_in[0];
    const float* emb  = (const float*)d_in[1];
    const float* bWih = (const float*)d_in[2];
    const float* bWhh = (const float*)d_in[3];
    const float* baW  = (const float*)d_in[4];
    const float* bab  = (const float*)d_in[5];
    const float* pWih = (const float*)d_in[6];
    const float* pWhh = (const float*)d_in[7];
    const float* paW  = (const float*)d_in[8];
    const float* pab  = (const float*)d_in[9];
    const float* cW   = (const float*)d_in[10];
    const float* cb   = (const float*)d_in[11];
    const float* h0b  = (const float*)d_in[12];
    const float* h0p  = (const float*)d_in[13];
    float* out = (float*)d_out;

    char* ws = (char*)d_ws;
    size_t off = 0;
    unsigned short* y = (unsigned short*)(ws + off); off += (size_t)SD * ND * 256 * 2; // 134 MiB
    float* hn    = (float*)(ws + off); off += (size_t)2 * ND * HD * 4;
    float* enc   = (float*)(ws + off); off += (size_t)ND * EP * 4;
    float* pxw   = (float*)(ws + off); off += (size_t)2 * PD * 32 * GD * 4;
    float* y2    = (float*)(ws + off); off += (size_t)PD * 32 * 256 * 4;
    float* hn2   = (float*)(ws + off); off += (size_t)2 * 32 * HD * 4;
    float* WihPp = (float*)(ws + off); off += (size_t)2 * GD * EP * 4;
    unsigned short* embHi = (unsigned short*)(ws + off); off += (size_t)VD * 64 * 2;   // 8.4 MiB
    if (ws_size < off) return;  // signature: output stays 0 => ws too small

    prep_emb<<<(VD * 64 + 255) / 256, 256, 0, stream>>>(emb, embHi);
    prep_pad_pkt<<<(2 * GD * EP + 255) / 256, 256, 0, stream>>>(pWih, WihPp);
    byte_gru_mfma<<<256, 512, 0, stream>>>(flow, embHi, bWih, bWhh, h0b, y, hn);
    byte_attn<<<ND, 256, 0, stream>>>((const __hip_bfloat16*)y, hn, baW, bab, enc);
    pkt_xw<<<256, 256, 0, stream>>>(enc, WihPp, pxw);
    pkt_gru<<<64, 384, 0, stream>>>(pxw, pWhh, h0p, y2, hn2);
    pkt_attn_cls<<<32, 256, 0, stream>>>(y2, hn2, paW, pab, cW, cb, out);
}

// Round 3
// 564.608 us; speedup vs baseline: 5.4049x; 1.0826x over previous
//
#include <hip/hip_runtime.h>
#include <hip/hip_bf16.h>

// Problem dims (fixed by reference)
#define PD 128   // packets
#define BD 32    // batch
#define SD 64    // bytes per packet (byte-GRU seq len)
#define ED 50    // embedding size
#define EP 52    // padded E (16B-aligned float4 rows)
#define HD 128   // hidden (byte and packet)
#define GD 384   // 3*H gates
#define ND 4096  // P*B byte-level batch
#define VD 65536 // vocab

typedef __attribute__((ext_vector_type(8))) short bf16x8;
typedef __attribute__((ext_vector_type(4))) float f32x4;

__device__ __forceinline__ float sigm(float x) { return 1.0f / (1.0f + __expf(-x)); }
__device__ __forceinline__ float tanh_f(float x) { return 1.0f - 2.0f / (__expf(2.0f * x) + 1.0f); }

__device__ __forceinline__ unsigned short f2b(float f) {  // f32 -> bf16 raw, RNE (prep kernels)
    union { float f; unsigned u; } a; a.f = f;
    unsigned r = a.u + 0x7FFFu + ((a.u >> 16) & 1u);
    return (unsigned short)(r >> 16);
}
__device__ __forceinline__ float b2f(unsigned short h) {
    union { unsigned u; float f; } a; a.u = ((unsigned)h) << 16; return a.f;
}

union frag_u { bf16x8 v; unsigned short s[8]; };

#define MFMA(acc, a, b) acc = __builtin_amdgcn_mfma_f32_16x16x32_bf16(a, b, acc, 0, 0, 0)

// Raw LDS-only barrier: does NOT drain vmcnt, so global stores/loads stay in
// flight across it. asm memory clobber fences IR-level motion; sched_barrier
// pins MIR scheduling (rule #18).
__device__ __forceinline__ void block_sync_lds() {
    asm volatile("s_waitcnt lgkmcnt(0)" ::: "memory");
    __builtin_amdgcn_sched_barrier(0);
    __builtin_amdgcn_s_barrier();
    __builtin_amdgcn_sched_barrier(0);
}

// ---------------------------------------------------------------------------
// Prep A: pad+convert embedding (V,50) f32 -> (V,64) bf16 plane (zero pad).
// ---------------------------------------------------------------------------
__global__ void prep_emb(const float* __restrict__ emb, unsigned short* __restrict__ embHi) {
    int idx = blockIdx.x * 256 + threadIdx.x;
    if (idx >= VD * 64) return;
    int row = idx >> 6, e = idx & 63;
    float v = (e < ED) ? emb[row * ED + e] : 0.f;
    embHi[idx] = f2b(v);
}

// ---------------------------------------------------------------------------
// Prep B: pad packet Wih rows (2,384,50) -> (2,384,52) for pkt_xw float4 path.
// ---------------------------------------------------------------------------
__global__ void prep_pad_pkt(const float* __restrict__ pw, float* __restrict__ pP) {
    int idx = blockIdx.x * 256 + threadIdx.x;
    if (idx >= 2 * GD * EP) return;
    int row = idx / EP, e = idx - row * EP;
    pP[idx] = (e < ED) ? pw[row * ED + e] : 0.f;
}

// ---------------------------------------------------------------------------
// K1: byte-level bi-GRU via MFMA, split-bf16 precision compensation.
// v3: double-buffered h planes + ONE raw (non-vmcnt-draining) barrier per
// step; x-fragments prefetched one step ahead; intrinsic bf16 converts.
// ---------------------------------------------------------------------------
__global__ __launch_bounds__(512, 2) void byte_gru_mfma(
    const int* __restrict__ flow, const unsigned short* __restrict__ embHi,
    const float* __restrict__ Wih, const float* __restrict__ Whh,
    const float* __restrict__ h0b,
    unsigned short* __restrict__ y, float* __restrict__ hn) {
    const int dir   = blockIdx.x >> 7;
    const int chunk = blockIdx.x & 127;
    const int n0    = chunk * 32;
    const int tid   = threadIdx.x;
    const int w     = tid >> 6;       // wave 0..7
    const int lane  = tid & 63;
    const int col   = lane & 15;      // C col / A row / B col
    const int kq    = lane >> 4;      // k quarter
    const int u     = w * 16 + col;   // owned unit

    __shared__ unsigned short HHI[2][32 * 128];
    __shared__ unsigned short HLO[2][32 * 128];
    __shared__ int FLOWT[SD * 32];

    // ---- weights -> register B-fragments (loaded once) ----
    bf16x8 WHh[3][4], WHl[3][4], WXh[3][2], WXl[3][2];
    {
        const float* WhhD = Whh + dir * GD * HD;
        #pragma unroll
        for (int g3 = 0; g3 < 3; ++g3) {
            const float* row = WhhD + (g3 * HD + u) * HD;
            #pragma unroll
            for (int kt = 0; kt < 4; ++kt) {
                const int k0 = kt * 32 + kq * 8;
                frag_u h_, l_;
                #pragma unroll
                for (int b = 0; b < 8; ++b) {
                    float v = row[k0 + b];
                    unsigned short hi = f2b(v);
                    h_.s[b] = hi; l_.s[b] = f2b(v - b2f(hi));
                }
                WHh[g3][kt] = h_.v; WHl[g3][kt] = l_.v;
            }
        }
        const float* WihD = Wih + dir * GD * ED;
        #pragma unroll
        for (int g3 = 0; g3 < 3; ++g3) {
            const float* row = WihD + (g3 * HD + u) * ED;
            #pragma unroll
            for (int kx = 0; kx < 2; ++kx) {
                const int k0 = kx * 32 + kq * 8;
                frag_u h_, l_;
                #pragma unroll
                for (int b = 0; b < 8; ++b) {
                    const int e = k0 + b;
                    float v = (e < ED) ? row[e] : 0.f;
                    unsigned short hi = f2b(v);
                    h_.s[b] = hi; l_.s[b] = f2b(v - b2f(hi));
                }
                WXh[g3][kx] = h_.v; WXl[g3][kx] = l_.v;
            }
        }
    }

    // ---- h0: registers (exact f32 for the z-blend) + LDS hi/lo planes ----
    float hreg[2][4];
    {
        const float* h0row = h0b + (size_t)((chunk * 2 + dir) * 32) * HD;
        #pragma unroll
        for (int m = 0; m < 2; ++m)
            #pragma unroll
            for (int j = 0; j < 4; ++j)
                hreg[m][j] = h0row[(m * 16 + kq * 4 + j) * HD + u];
        for (int idx = tid; idx < 32 * HD; idx += 512) {
            int seq = idx >> 7, uu = idx & 127;
            float v = h0row[idx];
            unsigned short hi = f2b(v);
            int sw = seq * 128 + (uu ^ ((seq & 7) << 3));
            HHI[0][sw] = hi; HLO[0][sw] = f2b(v - b2f(hi));
        }
        for (int j = tid; j < SD * 32; j += 512) {  // transposed flow cache
            int s = j >> 5, seq = j & 31;
            FLOWT[j] = flow[(n0 + seq) * SD + s];
        }
    }
    block_sync_lds();

    // prefetch x fragments for t=0
    bf16x8 xa00, xa01, xa10, xa11;
    {
        const int s0 = dir ? (SD - 1) : 0;
        int i0 = FLOWT[s0 * 32 + col];
        int i1 = FLOWT[s0 * 32 + 16 + col];
        const bf16x8* r0 = (const bf16x8*)(embHi + (size_t)i0 * 64);
        const bf16x8* r1 = (const bf16x8*)(embHi + (size_t)i1 * 64);
        xa00 = r0[kq]; xa01 = r0[4 + kq];
        xa10 = r1[kq]; xa11 = r1[4 + kq];
    }

    int par = 0;
    for (int t = 0; t < SD; ++t) {
        const int s = dir ? (SD - 1 - t) : t;

        // issue next step's x loads early (latency hides under h-MFMAs)
        bf16x8 xn00, xn01, xn10, xn11;
        const bool havenext = (t < SD - 1);
        if (havenext) {
            const int sn = dir ? (SD - 2 - t) : (t + 1);
            int i0 = FLOWT[sn * 32 + col];
            int i1 = FLOWT[sn * 32 + 16 + col];
            const bf16x8* r0 = (const bf16x8*)(embHi + (size_t)i0 * 64);
            const bf16x8* r1 = (const bf16x8*)(embHi + (size_t)i1 * 64);
            xn00 = r0[kq]; xn01 = r0[4 + kq];
            xn10 = r1[kq]; xn11 = r1[4 + kq];
        }

        f32x4 aR[2], aZ[2], aHN[2], aXN[2];
        const f32x4 zero = {0.f, 0.f, 0.f, 0.f};
        #pragma unroll
        for (int m = 0; m < 2; ++m) { aR[m] = zero; aZ[m] = zero; aHN[m] = zero; aXN[m] = zero; }

        // h-matvec: 4 k-tiles x 3 gates x 3 split-products x 2 m-tiles
        const unsigned short* HHIp = HHI[par];
        const unsigned short* HLOp = HLO[par];
        #pragma unroll
        for (int kt = 0; kt < 4; ++kt) {
            const int off = kt * 32 + kq * 8;
            const int sw0 = col * 128 + (off ^ ((col & 7) << 3));
            const int sw1 = sw0 + 16 * 128;   // seq+16 keeps (seq&7)
            bf16x8 ah0 = *(const bf16x8*)&HHIp[sw0];
            bf16x8 al0 = *(const bf16x8*)&HLOp[sw0];
            bf16x8 ah1 = *(const bf16x8*)&HHIp[sw1];
            bf16x8 al1 = *(const bf16x8*)&HLOp[sw1];
            MFMA(aR[0], ah0, WHh[0][kt]); MFMA(aR[0], al0, WHh[0][kt]); MFMA(aR[0], ah0, WHl[0][kt]);
            MFMA(aZ[0], ah0, WHh[1][kt]); MFMA(aZ[0], al0, WHh[1][kt]); MFMA(aZ[0], ah0, WHl[1][kt]);
            MFMA(aHN[0], ah0, WHh[2][kt]); MFMA(aHN[0], al0, WHh[2][kt]); MFMA(aHN[0], ah0, WHl[2][kt]);
            MFMA(aR[1], ah1, WHh[0][kt]); MFMA(aR[1], al1, WHh[0][kt]); MFMA(aR[1], ah1, WHl[0][kt]);
            MFMA(aZ[1], ah1, WHh[1][kt]); MFMA(aZ[1], al1, WHh[1][kt]); MFMA(aZ[1], ah1, WHl[1][kt]);
            MFMA(aHN[1], ah1, WHh[2][kt]); MFMA(aHN[1], al1, WHh[2][kt]); MFMA(aHN[1], ah1, WHl[2][kt]);
        }
        // x-projection: 2 k-tiles x 3 gates x 2 products x 2 m-tiles
        #pragma unroll
        for (int kx = 0; kx < 2; ++kx) {
            bf16x8 x0 = kx ? xa01 : xa00;
            bf16x8 x1 = kx ? xa11 : xa10;
            MFMA(aR[0], x0, WXh[0][kx]); MFMA(aR[0], x0, WXl[0][kx]);
            MFMA(aZ[0], x0, WXh[1][kx]); MFMA(aZ[0], x0, WXl[1][kx]);
            MFMA(aXN[0], x0, WXh[2][kx]); MFMA(aXN[0], x0, WXl[2][kx]);
            MFMA(aR[1], x1, WXh[0][kx]); MFMA(aR[1], x1, WXl[0][kx]);
            MFMA(aZ[1], x1, WXh[1][kx]); MFMA(aZ[1], x1, WXl[1][kx]);
            MFMA(aXN[1], x1, WXh[2][kx]); MFMA(aXN[1], x1, WXl[2][kx]);
        }

        // epilogue: gate math in C layout (col=u, row=(lane>>4)*4+j)
        unsigned short yhi[2][4];
        unsigned short ylo[2][4];
        #pragma unroll
        for (int m = 0; m < 2; ++m)
            #pragma unroll
            for (int j = 0; j < 4; ++j) {
                float r = sigm(aR[m][j]);
                float z = sigm(aZ[m][j]);
                float nn = tanh_f(aXN[m][j] + r * aHN[m][j]);
                float hnew = (1.f - z) * nn + z * hreg[m][j];
                hreg[m][j] = hnew;
                __hip_bfloat16 bh = __float2bfloat16(hnew);
                unsigned short hi = *(unsigned short*)&bh;
                __hip_bfloat16 bl = __float2bfloat16(hnew - b2f(hi));
                yhi[m][j] = hi;
                ylo[m][j] = *(unsigned short*)&bl;
            }
        // LDS writes first (drain while y stores issue)
        unsigned short* HHIn = HHI[par ^ 1];
        unsigned short* HLOn = HLO[par ^ 1];
        #pragma unroll
        for (int m = 0; m < 2; ++m)
            #pragma unroll
            for (int j = 0; j < 4; ++j) {
                int seq = m * 16 + kq * 4 + j;
                int sw = seq * 128 + (u ^ ((seq & 7) << 3));
                HHIn[sw] = yhi[m][j];
                HLOn[sw] = ylo[m][j];
            }
        // y stores: fire-and-forget, NOT drained at the raw barrier
        #pragma unroll
        for (int m = 0; m < 2; ++m)
            #pragma unroll
            for (int j = 0; j < 4; ++j) {
                int seq = m * 16 + kq * 4 + j;
                y[((size_t)(s * ND) + n0 + seq) * 256 + dir * HD + u] = yhi[m][j];
            }
        block_sync_lds();
        xa00 = xn00; xa01 = xn01; xa10 = xn10; xa11 = xn11;
        par ^= 1;
    }
    // final hidden (exact f32 path, from registers)
    #pragma unroll
    for (int m = 0; m < 2; ++m)
        #pragma unroll
        for (int j = 0; j < 4; ++j) {
            int seq = m * 16 + kq * 4 + j;
            hn[((size_t)dir * ND + n0 + seq) * HD + u] = hreg[m][j];
        }
}

// ---------------------------------------------------------------------------
// K2: byte attention + enc projection. Block = one (p,b) sequence.
// ---------------------------------------------------------------------------
__global__ __launch_bounds__(256) void byte_attn(
    const unsigned short* __restrict__ y, const float* __restrict__ hn,
    const float* __restrict__ aW, const float* __restrict__ ab,
    float* __restrict__ enc) {
    const int n = blockIdx.x;
    const int p = n >> 5, irow = n & 31;
    const int tid = threadIdx.x;
    __shared__ unsigned short yl[SD][256];
    __shared__ float hnl[256];
    __shared__ float red[256];
    __shared__ float awl[SD];
    __shared__ float ctxl[256];

    for (int idx = tid; idx < SD * 32; idx += 256) {
        int s = idx >> 5, cc = (idx & 31) * 8;
        *(uint4*)&yl[s][cc] = *(const uint4*)&y[((s * ND) + n) * 256 + cc];
    }
    {   // hn_p reshape quirk: flat idx = irow*256+c over (2,32,128)
        int c = tid;
        int idx = irow * 256 + c;
        int d = idx >> 12, bb = (idx >> 7) & 31, uu = idx & 127;
        hnl[c] = hn[(d * ND + p * 32 + bb) * HD + uu];
    }
    __syncthreads();
    {   // scores: 2-wide (u32 y-pair + float2 hnl), skewed to spread banks
        int s = tid & 63, grp = tid >> 6;
        float acc = 0.f;
        for (int k = 0; k < 32; ++k) {
            int c2 = grp * 32 + ((s + k) & 31);
            unsigned pair = *(const unsigned*)&yl[s][c2 * 2];
            float2 hv = *(const float2*)&hnl[c2 * 2];
            union { unsigned u; float f; } lo, hi;
            lo.u = pair << 16; hi.u = pair & 0xFFFF0000u;
            acc += lo.f * hv.x + hi.f * hv.y;
        }
        red[grp * 64 + s] = acc;
    }
    __syncthreads();
    if (tid < 64) {
        float sc = red[tid] + red[64 + tid] + red[128 + tid] + red[192 + tid];
        float m = sc;
        #pragma unroll
        for (int o = 32; o; o >>= 1) m = fmaxf(m, __shfl_xor(m, o));
        float e = __expf(sc - m);
        float ssum = e;
        #pragma unroll
        for (int o = 32; o; o >>= 1) ssum += __shfl_xor(ssum, o);
        awl[tid] = e / ssum;
    }
    __syncthreads();
    {
        int c = tid;
        float acc = 0.f;
        for (int s = 0; s < SD; ++s) acc += awl[s] * b2f(yl[s][c]);
        ctxl[c] = acc;
    }
    __syncthreads();
    {
        int e = tid & 63, q = tid >> 6;
        float acc = 0.f;
        if (e < ED) {
            for (int c = q * 64; c < q * 64 + 64; ++c) acc += ctxl[c] * aW[e * 256 + c];
        }
        red[q * 64 + e] = acc;
    }
    __syncthreads();
    if (tid < EP) {
        float v = 0.f;
        if (tid < ED) v = red[tid] + red[64 + tid] + red[128 + tid] + red[192 + tid] + ab[tid];
        enc[n * EP + tid] = v;
    }
}

// ---------------------------------------------------------------------------
// K2.5: packet-GRU input projection
// ---------------------------------------------------------------------------
__global__ __launch_bounds__(256, 1) void pkt_xw(
    const float* __restrict__ enc, const float* __restrict__ WihPp,
    float* __restrict__ pxw) {
    const int d = blockIdx.x >> 7, p = blockIdx.x & 127;
    const int tid = threadIdx.x;
    __shared__ float el[32][EP];
    for (int idx = tid; idx < 32 * EP; idx += 256) {
        int ii = idx / EP, e = idx - ii * EP;
        el[ii][e] = enc[(p * 32 + ii) * EP + e];
    }
    __syncthreads();
    const int irow = tid & 31, gg = tid >> 5;
    const float* W = WihPp + d * GD * EP;
    float acc[48];
    #pragma unroll
    for (int j = 0; j < 48; ++j) acc[j] = 0.f;
    for (int ec = 0; ec < 13; ++ec) {
        float4 x4 = *(const float4*)&el[irow][ec * 4];
        #pragma unroll
        for (int j = 0; j < 48; ++j) {
            float4 w4 = *(const float4*)(W + (gg + 8 * j) * EP + ec * 4);
            acc[j] += x4.x * w4.x + x4.y * w4.y + x4.z * w4.z + x4.w * w4.w;
        }
    }
    float* dst = pxw + (size_t)((d * PD + p) * 32 + irow) * GD;
    #pragma unroll
    for (int j = 0; j < 48; ++j) dst[gg + 8 * j] = acc[j];
}

// ---------------------------------------------------------------------------
// K3: packet-level bi-GRU. v3: xw prefetch one step ahead + raw barriers
// (y2 stores no longer drain at each of the 256 barriers).
// ---------------------------------------------------------------------------
__global__ __launch_bounds__(384, 1) void pkt_gru(
    const float* __restrict__ pxw, const float* __restrict__ Whh,
    const float* __restrict__ h0p,
    float* __restrict__ y2, float* __restrict__ hn2) {
    const int d = blockIdx.x >> 5, sq = blockIdx.x & 31;
    const int tid = threadIdx.x;
    __shared__ float hcur[HD];
    __shared__ float hw[GD];
    float w[HD];
    const float* wrow = Whh + (d * GD + tid) * HD;
    #pragma unroll
    for (int k = 0; k < HD; ++k) w[k] = wrow[k];
    if (tid < HD) hcur[tid] = h0p[(d * 32 + sq) * HD + tid];

    float xr = 0.f, xz = 0.f, xn_ = 0.f;
    if (tid < HD) {
        const int p0 = d ? (PD - 1) : 0;
        const float* xw = pxw + (size_t)((d * PD + p0) * 32 + sq) * GD;
        xr = xw[tid]; xz = xw[HD + tid]; xn_ = xw[2 * HD + tid];
    }
    block_sync_lds();
    for (int t = 0; t < PD; ++t) {
        const int pp = d ? (PD - 1 - t) : t;
        // prefetch next step's input projections
        float xrn = 0.f, xzn = 0.f, xnn = 0.f;
        if (t < PD - 1 && tid < HD) {
            const int pn = d ? (PD - 2 - t) : (t + 1);
            const float* xw = pxw + (size_t)((d * PD + pn) * 32 + sq) * GD;
            xrn = xw[tid]; xzn = xw[HD + tid]; xnn = xw[2 * HD + tid];
        }
        float a0 = 0.f, a1 = 0.f, a2 = 0.f, a3 = 0.f;
        #pragma unroll
        for (int kc = 0; kc < 32; ++kc) {
            float4 h4 = *(const float4*)&hcur[kc * 4];
            a0 += w[4 * kc + 0] * h4.x; a1 += w[4 * kc + 1] * h4.y;
            a2 += w[4 * kc + 2] * h4.z; a3 += w[4 * kc + 3] * h4.w;
        }
        hw[tid] = (a0 + a1) + (a2 + a3);
        block_sync_lds();
        if (tid < HD) {
            int uu = tid;
            float r = sigm(xr + hw[uu]);
            float z = sigm(xz + hw[HD + uu]);
            float nn = tanh_f(xn_ + r * hw[2 * HD + uu]);
            float hnew = (1.f - z) * nn + z * hcur[uu];
            hcur[uu] = hnew;
            y2[(pp * 32 + sq) * 256 + d * HD + uu] = hnew;  // not drained
        }
        block_sync_lds();
        xr = xrn; xz = xzn; xn_ = xnn;
    }
    if (tid < HD) hn2[(d * 32 + sq) * HD + tid] = hcur[tid];
}

// ---------------------------------------------------------------------------
// K4: packet attention + output head
// ---------------------------------------------------------------------------
__global__ __launch_bounds__(256) void pkt_attn_cls(
    const float* __restrict__ y2, const float* __restrict__ hn2,
    const float* __restrict__ aW, const float* __restrict__ ab,
    const float* __restrict__ cW, const float* __restrict__ cb,
    float* __restrict__ out) {
    const int b = blockIdx.x;
    const int tid = threadIdx.x;
    __shared__ float hnl[256];
    __shared__ float red[256];
    __shared__ float scl[PD];
    __shared__ float awl[PD];
    __shared__ float ctxl[256];
    __shared__ float ol[HD];
    {
        int c = tid;
        hnl[c] = hn2[(((b >> 4) * 32) + 2 * (b & 15) + (c >> 7)) * HD + (c & 127)];
    }
    __syncthreads();
    {
        int p2 = tid >> 1, hf = tid & 1;
        const float* yr = y2 + (p2 * 32 + b) * 256 + hf * 128;
        const float* hr = hnl + hf * 128;
        float acc = 0.f;
        for (int c = 0; c < 128; ++c) acc += yr[c] * hr[c];
        red[hf * 128 + p2] = acc;
    }
    __syncthreads();
    if (tid < PD) scl[tid] = red[tid] + red[128 + tid];
    __syncthreads();
    if (tid < 64) {
        float s0 = scl[tid], s1 = scl[64 + tid];
        float m = fmaxf(s0, s1);
        #pragma unroll
        for (int o = 32; o; o >>= 1) m = fmaxf(m, __shfl_xor(m, o));
        float e0 = __expf(s0 - m), e1 = __expf(s1 - m);
        float ss = e0 + e1;
        #pragma unroll
        for (int o = 32; o; o >>= 1) ss += __shfl_xor(ss, o);
        awl[tid] = e0 / ss; awl[64 + tid] = e1 / ss;
    }
    __syncthreads();
    {
        int c = tid;
        float acc = 0.f;
        for (int p2 = 0; p2 < PD; ++p2) acc += awl[p2] * y2[(p2 * 32 + b) * 256 + c];
        ctxl[c] = acc;
    }
    __syncthreads();
    {
        int h = tid >> 1, hf = tid & 1;
        const float* wr = aW + h * 256 + hf * 128;
        const float* cr = ctxl + hf * 128;
        float acc = 0.f;
        for (int c = 0; c < 128; ++c) acc += cr[c] * wr[c];
        red[hf * 128 + h] = acc;
    }
    __syncthreads();
    if (tid < HD) ol[tid] = red[tid] + red[128 + tid] + ab[tid];
    __syncthreads();
    if (tid < 11) {
        float acc = cb[tid];
        for (int h = 0; h < HD; ++h) acc += ol[h] * cW[tid * HD + h];
        out[b * 11 + tid] = acc;
    }
}

// ---------------------------------------------------------------------------
extern "C" void kernel_launch(void* const* d_in, const int* in_sizes, int n_in,
                              void* d_out, int out_size, void* d_ws, size_t ws_size,
                              hipStream_t stream) {
    const int*   flow = (const int*)d_in[0];
    const float* emb  = (const float*)d_in[1];
    const float* bWih = (const float*)d_in[2];
    const float* bWhh = (const float*)d_in[3];
    const float* baW  = (const float*)d_in[4];
    const float* bab  = (const float*)d_in[5];
    const float* pWih = (const float*)d_in[6];
    const float* pWhh = (const float*)d_in[7];
    const float* paW  = (const float*)d_in[8];
    const float* pab  = (const float*)d_in[9];
    const float* cW   = (const float*)d_in[10];
    const float* cb   = (const float*)d_in[11];
    const float* h0b  = (const float*)d_in[12];
    const float* h0p  = (const float*)d_in[13];
    float* out = (float*)d_out;

    char* ws = (char*)d_ws;
    size_t off = 0;
    unsigned short* y = (unsigned short*)(ws + off); off += (size_t)SD * ND * 256 * 2; // 134 MiB
    float* hn    = (float*)(ws + off); off += (size_t)2 * ND * HD * 4;
    float* enc   = (float*)(ws + off); off += (size_t)ND * EP * 4;
    float* pxw   = (float*)(ws + off); off += (size_t)2 * PD * 32 * GD * 4;
    float* y2    = (float*)(ws + off); off += (size_t)PD * 32 * 256 * 4;
    float* hn2   = (float*)(ws + off); off += (size_t)2 * 32 * HD * 4;
    float* WihPp = (float*)(ws + off); off += (size_t)2 * GD * EP * 4;
    unsigned short* embHi = (unsigned short*)(ws + off); off += (size_t)VD * 64 * 2;   // 8.4 MiB
    if (ws_size < off) return;  // signature: output stays 0 => ws too small

    prep_emb<<<(VD * 64 + 255) / 256, 256, 0, stream>>>(emb, embHi);
    prep_pad_pkt<<<(2 * GD * EP + 255) / 256, 256, 0, stream>>>(pWih, WihPp);
    byte_gru_mfma<<<256, 512, 0, stream>>>(flow, embHi, bWih, bWhh, h0b, y, hn);
    byte_attn<<<ND, 256, 0, stream>>>(y, hn, baW, bab, enc);
    pkt_xw<<<256, 256, 0, stream>>>(enc, WihPp, pxw);
    pkt_gru<<<64, 384, 0, stream>>>(pxw, pWhh, h0p, y2, hn2);
    pkt_attn_cls<<<32, 256, 0, stream>>>(y2, hn2, paW, pab, cW, cb, out);
}

// Round 4
// 540.172 us; speedup vs baseline: 5.6494x; 1.0452x over previous
//
#include <hip/hip_runtime.h>
#include <hip/hip_bf16.h>

// Problem dims (fixed by reference)
#define PD 128   // packets
#define BD 32    // batch
#define SD 64    // bytes per packet (byte-GRU seq len)
#define ED 50    // embedding size
#define EP 52    // padded E (16B-aligned float4 rows)
#define HD 128   // hidden (byte and packet)
#define GD 384   // 3*H gates
#define ND 4096  // P*B byte-level batch
#define VD 65536 // vocab

typedef __attribute__((ext_vector_type(8))) short bf16x8;
typedef __attribute__((ext_vector_type(4))) float f32x4;

__device__ __forceinline__ float sigm(float x) { return 1.0f / (1.0f + __expf(-x)); }
__device__ __forceinline__ float tanh_f(float x) { return 1.0f - 2.0f / (__expf(2.0f * x) + 1.0f); }

__device__ __forceinline__ unsigned short f2b(float f) {  // f32 -> bf16 raw, RNE (prep/init)
    union { float f; unsigned u; } a; a.f = f;
    unsigned r = a.u + 0x7FFFu + ((a.u >> 16) & 1u);
    return (unsigned short)(r >> 16);
}
__device__ __forceinline__ float b2f(unsigned short h) {
    union { unsigned u; float f; } a; a.u = ((unsigned)h) << 16; return a.f;
}

union frag_u { bf16x8 v; unsigned short s[8]; };

// Liveness pin: makes the fragment opaque so the compiler can neither
// rematerialize its construction inside the loop nor sink the loads.
__device__ __forceinline__ void pin(bf16x8& v) { asm volatile("" : "+v"(v)); }

#define MFMA(acc, a, b) acc = __builtin_amdgcn_mfma_f32_16x16x32_bf16(a, b, acc, 0, 0, 0)

// Raw LDS-only barrier: does NOT drain vmcnt, so global stores/loads stay in
// flight across it. asm memory clobber fences IR-level motion; sched_barrier
// pins MIR scheduling (rule #18).
__device__ __forceinline__ void block_sync_lds() {
    asm volatile("s_waitcnt lgkmcnt(0)" ::: "memory");
    __builtin_amdgcn_sched_barrier(0);
    __builtin_amdgcn_s_barrier();
    __builtin_amdgcn_sched_barrier(0);
}

// ---------------------------------------------------------------------------
// Prep A: pad+convert embedding (V,50) f32 -> (V,64) bf16 plane (zero pad).
// ---------------------------------------------------------------------------
__global__ void prep_emb(const float* __restrict__ emb, unsigned short* __restrict__ embHi) {
    int idx = blockIdx.x * 256 + threadIdx.x;
    if (idx >= VD * 64) return;
    int row = idx >> 6, e = idx & 63;
    float v = (e < ED) ? emb[row * ED + e] : 0.f;
    embHi[idx] = f2b(v);
}

// ---------------------------------------------------------------------------
// Prep B: pad packet Wih rows (2,384,50) -> (2,384,52) for pkt_xw float4 path.
// ---------------------------------------------------------------------------
__global__ void prep_pad_pkt(const float* __restrict__ pw, float* __restrict__ pP) {
    int idx = blockIdx.x * 256 + threadIdx.x;
    if (idx >= 2 * GD * EP) return;
    int row = idx / EP, e = idx - row * EP;
    pP[idx] = (e < ED) ? pw[row * ED + e] : 0.f;
}

// ---------------------------------------------------------------------------
// K1: byte-level bi-GRU via MFMA, split-bf16 precision compensation.
// v4: amdgpu_waves_per_eu(2,2) -> 256-VGPR budget so the 144 weight-fragment
// VGPRs stay RESIDENT across all 64 steps (v3's 128-VGPR choice made the
// compiler rematerialize the split-reconstruction per step: ~1000 extra VALU
// ops/thread-step = the observed VALUBusy 51%). pin() blocks remat.
// Grid is 256 blocks = 1 block/CU, so 2 waves/SIMD was the occupancy anyway.
// ---------------------------------------------------------------------------
__global__ __attribute__((amdgpu_flat_work_group_size(512, 512), amdgpu_waves_per_eu(2, 2)))
void byte_gru_mfma(
    const int* __restrict__ flow, const unsigned short* __restrict__ embHi,
    const float* __restrict__ Wih, const float* __restrict__ Whh,
    const float* __restrict__ h0b,
    unsigned short* __restrict__ y, float* __restrict__ hn) {
    const int dir   = blockIdx.x >> 7;
    const int chunk = blockIdx.x & 127;
    const int n0    = chunk * 32;
    const int tid   = threadIdx.x;
    const int w     = tid >> 6;       // wave 0..7
    const int lane  = tid & 63;
    const int col   = lane & 15;      // C col / A row / B col
    const int kq    = lane >> 4;      // k quarter
    const int u     = w * 16 + col;   // owned unit

    __shared__ unsigned short HHI[2][32 * 128];
    __shared__ unsigned short HLO[2][32 * 128];
    __shared__ int FLOWT[SD * 32];

    // ---- weights -> register B-fragments (loaded once, pinned live) ----
    bf16x8 WHh[3][4], WHl[3][4], WXh[3][2], WXl[3][2];
    {
        const float* WhhD = Whh + dir * GD * HD;
        #pragma unroll
        for (int g3 = 0; g3 < 3; ++g3) {
            const float* row = WhhD + (g3 * HD + u) * HD;
            #pragma unroll
            for (int kt = 0; kt < 4; ++kt) {
                const int k0 = kt * 32 + kq * 8;
                frag_u h_, l_;
                #pragma unroll
                for (int b = 0; b < 8; ++b) {
                    float v = row[k0 + b];
                    unsigned short hi = f2b(v);
                    h_.s[b] = hi; l_.s[b] = f2b(v - b2f(hi));
                }
                WHh[g3][kt] = h_.v; WHl[g3][kt] = l_.v;
                pin(WHh[g3][kt]); pin(WHl[g3][kt]);
            }
        }
        const float* WihD = Wih + dir * GD * ED;
        #pragma unroll
        for (int g3 = 0; g3 < 3; ++g3) {
            const float* row = WihD + (g3 * HD + u) * ED;
            #pragma unroll
            for (int kx = 0; kx < 2; ++kx) {
                const int k0 = kx * 32 + kq * 8;
                frag_u h_, l_;
                #pragma unroll
                for (int b = 0; b < 8; ++b) {
                    const int e = k0 + b;
                    float v = (e < ED) ? row[e] : 0.f;
                    unsigned short hi = f2b(v);
                    h_.s[b] = hi; l_.s[b] = f2b(v - b2f(hi));
                }
                WXh[g3][kx] = h_.v; WXl[g3][kx] = l_.v;
                pin(WXh[g3][kx]); pin(WXl[g3][kx]);
            }
        }
    }

    // ---- h0: registers (exact f32 for the z-blend) + LDS hi/lo planes ----
    float hreg[2][4];
    {
        const float* h0row = h0b + (size_t)((chunk * 2 + dir) * 32) * HD;
        #pragma unroll
        for (int m = 0; m < 2; ++m)
            #pragma unroll
            for (int j = 0; j < 4; ++j)
                hreg[m][j] = h0row[(m * 16 + kq * 4 + j) * HD + u];
        for (int idx = tid; idx < 32 * HD; idx += 512) {
            int seq = idx >> 7, uu = idx & 127;
            float v = h0row[idx];
            unsigned short hi = f2b(v);
            int sw = seq * 128 + (uu ^ ((seq & 7) << 3));
            HHI[0][sw] = hi; HLO[0][sw] = f2b(v - b2f(hi));
        }
        for (int j = tid; j < SD * 32; j += 512) {  // transposed flow cache
            int s = j >> 5, seq = j & 31;
            FLOWT[j] = flow[(n0 + seq) * SD + s];
        }
    }
    block_sync_lds();

    // prefetch x fragments for t=0
    bf16x8 xa00, xa01, xa10, xa11;
    {
        const int s0 = dir ? (SD - 1) : 0;
        int i0 = FLOWT[s0 * 32 + col];
        int i1 = FLOWT[s0 * 32 + 16 + col];
        const bf16x8* r0 = (const bf16x8*)(embHi + (size_t)i0 * 64);
        const bf16x8* r1 = (const bf16x8*)(embHi + (size_t)i1 * 64);
        xa00 = r0[kq]; xa01 = r0[4 + kq];
        xa10 = r1[kq]; xa11 = r1[4 + kq];
    }

    int par = 0;
    for (int t = 0; t < SD; ++t) {
        const int s = dir ? (SD - 1 - t) : t;

        // issue next step's x loads early (latency hides under h-MFMAs)
        bf16x8 xn00, xn01, xn10, xn11;
        const bool havenext = (t < SD - 1);
        if (havenext) {
            const int sn = dir ? (SD - 2 - t) : (t + 1);
            int i0 = FLOWT[sn * 32 + col];
            int i1 = FLOWT[sn * 32 + 16 + col];
            const bf16x8* r0 = (const bf16x8*)(embHi + (size_t)i0 * 64);
            const bf16x8* r1 = (const bf16x8*)(embHi + (size_t)i1 * 64);
            xn00 = r0[kq]; xn01 = r0[4 + kq];
            xn10 = r1[kq]; xn11 = r1[4 + kq];
        }

        f32x4 aR[2], aZ[2], aHN[2], aXN[2];
        const f32x4 zero = {0.f, 0.f, 0.f, 0.f};
        #pragma unroll
        for (int m = 0; m < 2; ++m) { aR[m] = zero; aZ[m] = zero; aHN[m] = zero; aXN[m] = zero; }

        // h-matvec: 4 k-tiles x 3 gates x 3 split-products x 2 m-tiles
        const unsigned short* HHIp = HHI[par];
        const unsigned short* HLOp = HLO[par];
        #pragma unroll
        for (int kt = 0; kt < 4; ++kt) {
            const int off = kt * 32 + kq * 8;
            const int sw0 = col * 128 + (off ^ ((col & 7) << 3));
            const int sw1 = sw0 + 16 * 128;   // seq+16 keeps (seq&7)
            bf16x8 ah0 = *(const bf16x8*)&HHIp[sw0];
            bf16x8 al0 = *(const bf16x8*)&HLOp[sw0];
            bf16x8 ah1 = *(const bf16x8*)&HHIp[sw1];
            bf16x8 al1 = *(const bf16x8*)&HLOp[sw1];
            MFMA(aR[0], ah0, WHh[0][kt]); MFMA(aR[0], al0, WHh[0][kt]); MFMA(aR[0], ah0, WHl[0][kt]);
            MFMA(aZ[0], ah0, WHh[1][kt]); MFMA(aZ[0], al0, WHh[1][kt]); MFMA(aZ[0], ah0, WHl[1][kt]);
            MFMA(aHN[0], ah0, WHh[2][kt]); MFMA(aHN[0], al0, WHh[2][kt]); MFMA(aHN[0], ah0, WHl[2][kt]);
            MFMA(aR[1], ah1, WHh[0][kt]); MFMA(aR[1], al1, WHh[0][kt]); MFMA(aR[1], ah1, WHl[0][kt]);
            MFMA(aZ[1], ah1, WHh[1][kt]); MFMA(aZ[1], al1, WHh[1][kt]); MFMA(aZ[1], ah1, WHl[1][kt]);
            MFMA(aHN[1], ah1, WHh[2][kt]); MFMA(aHN[1], al1, WHh[2][kt]); MFMA(aHN[1], ah1, WHl[2][kt]);
        }
        // x-projection: 2 k-tiles x 3 gates x 2 products x 2 m-tiles
        #pragma unroll
        for (int kx = 0; kx < 2; ++kx) {
            bf16x8 x0 = kx ? xa01 : xa00;
            bf16x8 x1 = kx ? xa11 : xa10;
            MFMA(aR[0], x0, WXh[0][kx]); MFMA(aR[0], x0, WXl[0][kx]);
            MFMA(aZ[0], x0, WXh[1][kx]); MFMA(aZ[0], x0, WXl[1][kx]);
            MFMA(aXN[0], x0, WXh[2][kx]); MFMA(aXN[0], x0, WXl[2][kx]);
            MFMA(aR[1], x1, WXh[0][kx]); MFMA(aR[1], x1, WXl[0][kx]);
            MFMA(aZ[1], x1, WXh[1][kx]); MFMA(aZ[1], x1, WXl[1][kx]);
            MFMA(aXN[1], x1, WXh[2][kx]); MFMA(aXN[1], x1, WXl[2][kx]);
        }

        // epilogue: gate math in C layout (col=u, row=(lane>>4)*4+j)
        unsigned short yhi[2][4];
        unsigned short ylo[2][4];
        #pragma unroll
        for (int m = 0; m < 2; ++m)
            #pragma unroll
            for (int j = 0; j < 4; ++j) {
                float r = sigm(aR[m][j]);
                float z = sigm(aZ[m][j]);
                float nn = tanh_f(aXN[m][j] + r * aHN[m][j]);
                float hnew = (1.f - z) * nn + z * hreg[m][j];
                hreg[m][j] = hnew;
                __hip_bfloat16 bh = __float2bfloat16(hnew);
                unsigned short hi = *(unsigned short*)&bh;
                __hip_bfloat16 bl = __float2bfloat16(hnew - b2f(hi));
                yhi[m][j] = hi;
                ylo[m][j] = *(unsigned short*)&bl;
            }
        // LDS writes first (drain while y stores issue)
        unsigned short* HHIn = HHI[par ^ 1];
        unsigned short* HLOn = HLO[par ^ 1];
        #pragma unroll
        for (int m = 0; m < 2; ++m)
            #pragma unroll
            for (int j = 0; j < 4; ++j) {
                int seq = m * 16 + kq * 4 + j;
                int sw = seq * 128 + (u ^ ((seq & 7) << 3));
                HHIn[sw] = yhi[m][j];
                HLOn[sw] = ylo[m][j];
            }
        // y stores: fire-and-forget, NOT drained at the raw barrier
        #pragma unroll
        for (int m = 0; m < 2; ++m)
            #pragma unroll
            for (int j = 0; j < 4; ++j) {
                int seq = m * 16 + kq * 4 + j;
                y[((size_t)(s * ND) + n0 + seq) * 256 + dir * HD + u] = yhi[m][j];
            }
        block_sync_lds();
        xa00 = xn00; xa01 = xn01; xa10 = xn10; xa11 = xn11;
        par ^= 1;
    }
    // final hidden (exact f32 path, from registers)
    #pragma unroll
    for (int m = 0; m < 2; ++m)
        #pragma unroll
        for (int j = 0; j < 4; ++j) {
            int seq = m * 16 + kq * 4 + j;
            hn[((size_t)dir * ND + n0 + seq) * HD + u] = hreg[m][j];
        }
}

// ---------------------------------------------------------------------------
// K2: byte attention + enc projection. Block = one (p,b) sequence.
// ---------------------------------------------------------------------------
__global__ __launch_bounds__(256) void byte_attn(
    const unsigned short* __restrict__ y, const float* __restrict__ hn,
    const float* __restrict__ aW, const float* __restrict__ ab,
    float* __restrict__ enc) {
    const int n = blockIdx.x;
    const int p = n >> 5, irow = n & 31;
    const int tid = threadIdx.x;
    __shared__ unsigned short yl[SD][256];
    __shared__ float hnl[256];
    __shared__ float red[256];
    __shared__ float awl[SD];
    __shared__ float ctxl[256];

    for (int idx = tid; idx < SD * 32; idx += 256) {
        int s = idx >> 5, cc = (idx & 31) * 8;
        *(uint4*)&yl[s][cc] = *(const uint4*)&y[((s * ND) + n) * 256 + cc];
    }
    {   // hn_p reshape quirk: flat idx = irow*256+c over (2,32,128)
        int c = tid;
        int idx = irow * 256 + c;
        int d = idx >> 12, bb = (idx >> 7) & 31, uu = idx & 127;
        hnl[c] = hn[(d * ND + p * 32 + bb) * HD + uu];
    }
    __syncthreads();
    {   // scores: 2-wide (u32 y-pair + float2 hnl), skewed to spread banks
        int s = tid & 63, grp = tid >> 6;
        float acc = 0.f;
        for (int k = 0; k < 32; ++k) {
            int c2 = grp * 32 + ((s + k) & 31);
            unsigned pair = *(const unsigned*)&yl[s][c2 * 2];
            float2 hv = *(const float2*)&hnl[c2 * 2];
            union { unsigned u; float f; } lo, hi;
            lo.u = pair << 16; hi.u = pair & 0xFFFF0000u;
            acc += lo.f * hv.x + hi.f * hv.y;
        }
        red[grp * 64 + s] = acc;
    }
    __syncthreads();
    if (tid < 64) {
        float sc = red[tid] + red[64 + tid] + red[128 + tid] + red[192 + tid];
        float m = sc;
        #pragma unroll
        for (int o = 32; o; o >>= 1) m = fmaxf(m, __shfl_xor(m, o));
        float e = __expf(sc - m);
        float ssum = e;
        #pragma unroll
        for (int o = 32; o; o >>= 1) ssum += __shfl_xor(ssum, o);
        awl[tid] = e / ssum;
    }
    __syncthreads();
    {
        int c = tid;
        float acc = 0.f;
        for (int s = 0; s < SD; ++s) acc += awl[s] * b2f(yl[s][c]);
        ctxl[c] = acc;
    }
    __syncthreads();
    {
        int e = tid & 63, q = tid >> 6;
        float acc = 0.f;
        if (e < ED) {
            for (int c = q * 64; c < q * 64 + 64; ++c) acc += ctxl[c] * aW[e * 256 + c];
        }
        red[q * 64 + e] = acc;
    }
    __syncthreads();
    if (tid < EP) {
        float v = 0.f;
        if (tid < ED) v = red[tid] + red[64 + tid] + red[128 + tid] + red[192 + tid] + ab[tid];
        enc[n * EP + tid] = v;
    }
}

// ---------------------------------------------------------------------------
// K2.5: packet-GRU input projection
// ---------------------------------------------------------------------------
__global__ __launch_bounds__(256, 1) void pkt_xw(
    const float* __restrict__ enc, const float* __restrict__ WihPp,
    float* __restrict__ pxw) {
    const int d = blockIdx.x >> 7, p = blockIdx.x & 127;
    const int tid = threadIdx.x;
    __shared__ float el[32][EP];
    for (int idx = tid; idx < 32 * EP; idx += 256) {
        int ii = idx / EP, e = idx - ii * EP;
        el[ii][e] = enc[(p * 32 + ii) * EP + e];
    }
    __syncthreads();
    const int irow = tid & 31, gg = tid >> 5;
    const float* W = WihPp + d * GD * EP;
    float acc[48];
    #pragma unroll
    for (int j = 0; j < 48; ++j) acc[j] = 0.f;
    for (int ec = 0; ec < 13; ++ec) {
        float4 x4 = *(const float4*)&el[irow][ec * 4];
        #pragma unroll
        for (int j = 0; j < 48; ++j) {
            float4 w4 = *(const float4*)(W + (gg + 8 * j) * EP + ec * 4);
            acc[j] += x4.x * w4.x + x4.y * w4.y + x4.z * w4.z + x4.w * w4.w;
        }
    }
    float* dst = pxw + (size_t)((d * PD + p) * 32 + irow) * GD;
    #pragma unroll
    for (int j = 0; j < 48; ++j) dst[gg + 8 * j] = acc[j];
}

// ---------------------------------------------------------------------------
// K3: packet-level bi-GRU. xw prefetch one step ahead + raw barriers
// (y2 stores do not drain at each of the 256 barriers).
// ---------------------------------------------------------------------------
__global__ __launch_bounds__(384, 1) void pkt_gru(
    const float* __restrict__ pxw, const float* __restrict__ Whh,
    const float* __restrict__ h0p,
    float* __restrict__ y2, float* __restrict__ hn2) {
    const int d = blockIdx.x >> 5, sq = blockIdx.x & 31;
    const int tid = threadIdx.x;
    __shared__ float hcur[HD];
    __shared__ float hw[GD];
    float w[HD];
    const float* wrow = Whh + (d * GD + tid) * HD;
    #pragma unroll
    for (int k = 0; k < HD; ++k) w[k] = wrow[k];
    if (tid < HD) hcur[tid] = h0p[(d * 32 + sq) * HD + tid];

    float xr = 0.f, xz = 0.f, xn_ = 0.f;
    if (tid < HD) {
        const int p0 = d ? (PD - 1) : 0;
        const float* xw = pxw + (size_t)((d * PD + p0) * 32 + sq) * GD;
        xr = xw[tid]; xz = xw[HD + tid]; xn_ = xw[2 * HD + tid];
    }
    block_sync_lds();
    for (int t = 0; t < PD; ++t) {
        const int pp = d ? (PD - 1 - t) : t;
        // prefetch next step's input projections
        float xrn = 0.f, xzn = 0.f, xnn = 0.f;
        if (t < PD - 1 && tid < HD) {
            const int pn = d ? (PD - 2 - t) : (t + 1);
            const float* xw = pxw + (size_t)((d * PD + pn) * 32 + sq) * GD;
            xrn = xw[tid]; xzn = xw[HD + tid]; xnn = xw[2 * HD + tid];
        }
        float a0 = 0.f, a1 = 0.f, a2 = 0.f, a3 = 0.f;
        #pragma unroll
        for (int kc = 0; kc < 32; ++kc) {
            float4 h4 = *(const float4*)&hcur[kc * 4];
            a0 += w[4 * kc + 0] * h4.x; a1 += w[4 * kc + 1] * h4.y;
            a2 += w[4 * kc + 2] * h4.z; a3 += w[4 * kc + 3] * h4.w;
        }
        hw[tid] = (a0 + a1) + (a2 + a3);
        block_sync_lds();
        if (tid < HD) {
            int uu = tid;
            float r = sigm(xr + hw[uu]);
            float z = sigm(xz + hw[HD + uu]);
            float nn = tanh_f(xn_ + r * hw[2 * HD + uu]);
            float hnew = (1.f - z) * nn + z * hcur[uu];
            hcur[uu] = hnew;
            y2[(pp * 32 + sq) * 256 + d * HD + uu] = hnew;  // not drained
        }
        block_sync_lds();
        xr = xrn; xz = xzn; xn_ = xnn;
    }
    if (tid < HD) hn2[(d * 32 + sq) * HD + tid] = hcur[tid];
}

// ---------------------------------------------------------------------------
// K4: packet attention + output head
// ---------------------------------------------------------------------------
__global__ __launch_bounds__(256) void pkt_attn_cls(
    const float* __restrict__ y2, const float* __restrict__ hn2,
    const float* __restrict__ aW, const float* __restrict__ ab,
    const float* __restrict__ cW, const float* __restrict__ cb,
    float* __restrict__ out) {
    const int b = blockIdx.x;
    const int tid = threadIdx.x;
    __shared__ float hnl[256];
    __shared__ float red[256];
    __shared__ float scl[PD];
    __shared__ float awl[PD];
    __shared__ float ctxl[256];
    __shared__ float ol[HD];
    {
        int c = tid;
        hnl[c] = hn2[(((b >> 4) * 32) + 2 * (b & 15) + (c >> 7)) * HD + (c & 127)];
    }
    __syncthreads();
    {
        int p2 = tid >> 1, hf = tid & 1;
        const float* yr = y2 + (p2 * 32 + b) * 256 + hf * 128;
        const float* hr = hnl + hf * 128;
        float acc = 0.f;
        for (int c = 0; c < 128; ++c) acc += yr[c] * hr[c];
        red[hf * 128 + p2] = acc;
    }
    __syncthreads();
    if (tid < PD) scl[tid] = red[tid] + red[128 + tid];
    __syncthreads();
    if (tid < 64) {
        float s0 = scl[tid], s1 = scl[64 + tid];
        float m = fmaxf(s0, s1);
        #pragma unroll
        for (int o = 32; o; o >>= 1) m = fmaxf(m, __shfl_xor(m, o));
        float e0 = __expf(s0 - m), e1 = __expf(s1 - m);
        float ss = e0 + e1;
        #pragma unroll
        for (int o = 32; o; o >>= 1) ss += __shfl_xor(ss, o);
        awl[tid] = e0 / ss; awl[64 + tid] = e1 / ss;
    }
    __syncthreads();
    {
        int c = tid;
        float acc = 0.f;
        for (int p2 = 0; p2 < PD; ++p2) acc += awl[p2] * y2[(p2 * 32 + b) * 256 + c];
        ctxl[c] = acc;
    }
    __syncthreads();
    {
        int h = tid >> 1, hf = tid & 1;
        const float* wr = aW + h * 256 + hf * 128;
        const float* cr = ctxl + hf * 128;
        float acc = 0.f;
        for (int c = 0; c < 128; ++c) acc += cr[c] * wr[c];
        red[hf * 128 + h] = acc;
    }
    __syncthreads();
    if (tid < HD) ol[tid] = red[tid] + red[128 + tid] + ab[tid];
    __syncthreads();
    if (tid < 11) {
        float acc = cb[tid];
        for (int h = 0; h < HD; ++h) acc += ol[h] * cW[tid * HD + h];
        out[b * 11 + tid] = acc;
    }
}

// ---------------------------------------------------------------------------
extern "C" void kernel_launch(void* const* d_in, const int* in_sizes, int n_in,
                              void* d_out, int out_size, void* d_ws, size_t ws_size,
                              hipStream_t stream) {
    const int*   flow = (const int*)d_in[0];
    const float* emb  = (const float*)d_in[1];
    const float* bWih = (const float*)d_in[2];
    const float* bWhh = (const float*)d_in[3];
    const float* baW  = (const float*)d_in[4];
    const float* bab  = (const float*)d_in[5];
    const float* pWih = (const float*)d_in[6];
    const float* pWhh = (const float*)d_in[7];
    const float* paW  = (const float*)d_in[8];
    const float* pab  = (const float*)d_in[9];
    const float* cW   = (const float*)d_in[10];
    const float* cb   = (const float*)d_in[11];
    const float* h0b  = (const float*)d_in[12];
    const float* h0p  = (const float*)d_in[13];
    float* out = (float*)d_out;

    char* ws = (char*)d_ws;
    size_t off = 0;
    unsigned short* y = (unsigned short*)(ws + off); off += (size_t)SD * ND * 256 * 2; // 134 MiB
    float* hn    = (float*)(ws + off); off += (size_t)2 * ND * HD * 4;
    float* enc   = (float*)(ws + off); off += (size_t)ND * EP * 4;
    float* pxw   = (float*)(ws + off); off += (size_t)2 * PD * 32 * GD * 4;
    float* y2    = (float*)(ws + off); off += (size_t)PD * 32 * 256 * 4;
    float* hn2   = (float*)(ws + off); off += (size_t)2 * 32 * HD * 4;
    float* WihPp = (float*)(ws + off); off += (size_t)2 * GD * EP * 4;
    unsigned short* embHi = (unsigned short*)(ws + off); off += (size_t)VD * 64 * 2;   // 8.4 MiB
    if (ws_size < off) return;  // signature: output stays 0 => ws too small

    prep_emb<<<(VD * 64 + 255) / 256, 256, 0, stream>>>(emb, embHi);
    prep_pad_pkt<<<(2 * GD * EP + 255) / 256, 256, 0, stream>>>(pWih, WihPp);
    byte_gru_mfma<<<256, 512, 0, stream>>>(flow, embHi, bWih, bWhh, h0b, y, hn);
    byte_attn<<<ND, 256, 0, stream>>>(y, hn, baW, bab, enc);
    pkt_xw<<<256, 256, 0, stream>>>(enc, WihPp, pxw);
    pkt_gru<<<64, 384, 0, stream>>>(pxw, pWhh, h0p, y2, hn2);
    pkt_attn_cls<<<32, 256, 0, stream>>>(y2, hn2, paW, pab, cW, cb, out);
}